// Round 2
// baseline (334.130 us; speedup 1.0000x reference)
//
#include <hip/hip_runtime.h>
#include <hip/hip_bf16.h>

// Problem: B=2, S=2048, D_MODEL=1024, H=16, DK=64.
// out = ((l2norm(Q Wq^T) l2norm(K Wk^T)^T)^2 (V Wv^T)) Wo^T   (per head)
// Inputs/outputs are fp32 (reference dtype). Internally: convert once to
// bf16 in d_ws, run bf16-MFMA pipeline with fp32 accumulation, store fp32.

#define D_MODEL 1024
#define N_HEADS 16
#define D_K     64
#define BATCH   2
#define SEQ     2048
#define M_TOT   (BATCH * SEQ)   // 4096

typedef short  s16x8 __attribute__((ext_vector_type(8)));   // 8 bf16 = 4 VGPR (MFMA A/B frag)
typedef float  f32x4 __attribute__((ext_vector_type(4)));   // MFMA C/D frag
typedef unsigned short ushort_t;
typedef ushort_t us4 __attribute__((ext_vector_type(4)));

__device__ __forceinline__ ushort_t f2bf(float f) {
    union { float f; unsigned int u; } x; x.f = f;
    unsigned int u = x.u;
    return (ushort_t)((u + 0x7fffu + ((u >> 16) & 1u)) >> 16);  // RNE
}
__device__ __forceinline__ float bf2f(ushort_t h) {
    union { unsigned int u; float f; } x; x.u = ((unsigned int)h) << 16;
    return x.f;
}

// ---------------------------------------------------------------------------
// fp32 -> bf16 conversion for all 11 input tensors in one launch.
// blockIdx.y = tensor id; grid.x sized for the largest tensor, small tensors
// early-exit. 4 elements (1 float4) per thread.
// ---------------------------------------------------------------------------
struct ConvArgs {
    const float* src[11];
    ushort_t*    dst[11];
    int          n[11];
};

__global__ __launch_bounds__(256) void convert_kernel(ConvArgs a) {
    const int t = blockIdx.y;
    const int i = (blockIdx.x * 256 + threadIdx.x) * 4;
    if (i >= a.n[t]) return;
    const float4 v = *(const float4*)(a.src[t] + i);
    us4 p;
    p[0] = f2bf(v.x); p[1] = f2bf(v.y); p[2] = f2bf(v.z); p[3] = f2bf(v.w);
    *(us4*)(a.dst[t] + i) = p;
}

// ---------------------------------------------------------------------------
// GEMM: C[m][n] = sum_k A[m][k] * W[n][k] + bias[n]   (torch Linear; W is
// row-major n-major == exactly the MFMA-native B^T form). A,W,bias bf16.
// 128x128 tile, 4 waves in 2x2, each wave owns a 64x64 sub-tile.
// MODE 0: fp32 row-major store to outf (output projection)
// MODE 1: fused per-head L2 row-norm, bf16 store to (B,H,S,DK) (q/k)
// MODE 2: bf16 store transposed per head to (B,H,DK,S) (v -> vT)
// ---------------------------------------------------------------------------
template <int MODE>
__global__ __launch_bounds__(256) void gemm_kernel(
    const ushort_t* __restrict__ A,
    const ushort_t* __restrict__ W,
    const ushort_t* __restrict__ bias,
    ushort_t* __restrict__ out,
    float* __restrict__ outf)
{
    constexpr int K = 1024;
    constexpr int SMEM_WORDS = (MODE == 2) ? (4 * 64 * 72) : (2 * 128 * 64);
    __shared__ __align__(16) ushort_t smem[SMEM_WORDS];
    ushort_t* Ast = smem;            // [128][64] bf16, K-contiguous
    ushort_t* Bst = smem + 128 * 64; // [128][64]

    const int t    = threadIdx.x;
    const int wave = t >> 6;
    const int lane = t & 63;
    const int quad = lane >> 4;
    const int lc   = lane & 15;
    const int wm   = wave >> 1;   // wave row (0..1)
    const int wn   = wave & 1;    // wave col (0..1)
    const int m0   = blockIdx.x * 128;
    const int n0   = blockIdx.y * 128;

    f32x4 acc[4][4];
    const f32x4 zero = {0.f, 0.f, 0.f, 0.f};
#pragma unroll
    for (int i = 0; i < 4; ++i)
#pragma unroll
        for (int j = 0; j < 4; ++j) acc[i][j] = zero;

    for (int k0 = 0; k0 < K; k0 += 64) {
        // stage A-tile and B-tile: 1024 x 16B each, 256 threads x 4 chunks
#pragma unroll
        for (int c = 0; c < 4; ++c) {
            int idx = c * 256 + t;
            int row = idx >> 3;
            int col = (idx & 7) * 8;
            *(uint4*)(Ast + row * 64 + col) =
                *(const uint4*)(A + (size_t)(m0 + row) * K + k0 + col);
            *(uint4*)(Bst + row * 64 + col) =
                *(const uint4*)(W + (size_t)(n0 + row) * K + k0 + col);
        }
        __syncthreads();
#pragma unroll
        for (int ks = 0; ks < 2; ++ks) {
            s16x8 a[4], b[4];
#pragma unroll
            for (int i = 0; i < 4; ++i) {
                a[i] = *(const s16x8*)(Ast + (wm * 64 + i * 16 + lc) * 64 + ks * 32 + quad * 8);
                b[i] = *(const s16x8*)(Bst + (wn * 64 + i * 16 + lc) * 64 + ks * 32 + quad * 8);
            }
#pragma unroll
            for (int mf = 0; mf < 4; ++mf)
#pragma unroll
                for (int nf = 0; nf < 4; ++nf)
                    acc[mf][nf] = __builtin_amdgcn_mfma_f32_16x16x32_bf16(
                        a[mf], b[nf], acc[mf][nf], 0, 0, 0);
        }
        __syncthreads();
    }

    // bias per nf (bias is zeros in this test but apply generally)
    float bv[4];
#pragma unroll
    for (int nf = 0; nf < 4; ++nf) bv[nf] = bf2f(bias[n0 + wn * 64 + nf * 16 + lc]);

    if (MODE == 0) {
#pragma unroll
        for (int mf = 0; mf < 4; ++mf)
#pragma unroll
            for (int nf = 0; nf < 4; ++nf)
#pragma unroll
                for (int r = 0; r < 4; ++r) {
                    int mg = m0 + wm * 64 + mf * 16 + quad * 4 + r;
                    int ng = n0 + wn * 64 + nf * 16 + lc;
                    outf[(size_t)mg * D_MODEL + ng] = acc[mf][nf][r] + bv[nf];
                }
    } else if (MODE == 1) {
        // wave's 64 cols == exactly one head; row m's 64 values live in the
        // 16 lanes of this quad x 4 nf regs -> butterfly over lane bits 0..3
#pragma unroll
        for (int mf = 0; mf < 4; ++mf)
#pragma unroll
            for (int r = 0; r < 4; ++r) {
                float ss = 0.f;
#pragma unroll
                for (int nf = 0; nf < 4; ++nf) {
                    float v = acc[mf][nf][r] + bv[nf];
                    acc[mf][nf][r] = v;
                    ss += v * v;
                }
                ss += __shfl_xor(ss, 1);
                ss += __shfl_xor(ss, 2);
                ss += __shfl_xor(ss, 4);
                ss += __shfl_xor(ss, 8);
                float inv = rsqrtf(ss + 1e-8f);
                int mg = m0 + wm * 64 + mf * 16 + quad * 4 + r;
                int b  = mg >> 11;        // /2048
                int s  = mg & 2047;
#pragma unroll
                for (int nf = 0; nf < 4; ++nf) {
                    int ng = n0 + wn * 64 + nf * 16 + lc;
                    int h = ng >> 6, d = ng & 63;
                    out[(((size_t)(b * N_HEADS + h)) * SEQ + s) * D_K + d] =
                        f2bf(acc[mf][nf][r] * inv);
                }
            }
    } else {
        // MODE 2: transpose wave's 64(s) x 64(d) tile through LDS, store vT.
        // Per-wave region [64 d][stride 72]; __syncthreads between write and
        // read (cross-lane LDS exchange needs a real barrier per HIP memory
        // model, even within one wave).
        ushort_t* vt = smem + wave * (64 * 72);
        __syncthreads();   // all Ast/Bst reads done before overwrite
#pragma unroll
        for (int mf = 0; mf < 4; ++mf)
#pragma unroll
            for (int nf = 0; nf < 4; ++nf) {
                us4 p;
#pragma unroll
                for (int r = 0; r < 4; ++r) p[r] = f2bf(acc[mf][nf][r] + bv[nf]);
                // d = nf*16+lc, s = mf*16+quad*4 .. +3
                *(us4*)(vt + (nf * 16 + lc) * 72 + mf * 16 + quad * 4) = p;
            }
        __syncthreads();
#pragma unroll
        for (int r = 0; r < 8; ++r) {
            int d  = r * 8 + (lane >> 3);
            int so = (lane & 7) * 8;
            uint4 val = *(const uint4*)(vt + d * 72 + so);
            int mg = m0 + wm * 64 + so;          // 8 consecutive s, same batch
            int b  = mg >> 11;
            int s  = mg & 2047;
            int ng = n0 + wn * 64 + d;
            int h = ng >> 6, dh = ng & 63;
            *(uint4*)(out + (((size_t)(b * N_HEADS + h)) * D_K + dh) * SEQ + s) = val;
        }
    }
}

// ---------------------------------------------------------------------------
// Attention: per (b,h): out = (qn kn^T)^2 v.  No softmax -> pure k-tiling.
// 4 waves x 32 q-rows = 128 q-tile. k-tiles of 64. P matrix relayout
// C-layout -> A-layout via per-wave LDS regions with block barriers.
// ---------------------------------------------------------------------------
__global__ __launch_bounds__(256) void attn_kernel(
    const ushort_t* __restrict__ qn,
    const ushort_t* __restrict__ kn,
    const ushort_t* __restrict__ vT,
    ushort_t* __restrict__ attn_out)
{
    __shared__ __align__(16) ushort_t asm_[4 * 32 * 72];

    const int t    = threadIdx.x;
    const int wave = t >> 6;
    const int lane = t & 63;
    const int quad = lane >> 4;
    const int lc   = lane & 15;
    const int qt   = blockIdx.x;       // q-tile (0..15)
    const int bh   = blockIdx.y;       // b*16+h (0..31)
    const int b    = bh >> 4;
    const int h    = bh & 15;

    const ushort_t* qb = qn + (size_t)bh * SEQ * D_K;
    const ushort_t* kb = kn + (size_t)bh * SEQ * D_K;
    const ushort_t* vb = vT + (size_t)bh * D_K * SEQ;
    const int q0 = qt * 128 + wave * 32;

    // preload q a-frags (reused over all 32 k-tiles)
    s16x8 aq[2][2];
#pragma unroll
    for (int mf = 0; mf < 2; ++mf)
#pragma unroll
        for (int ks = 0; ks < 2; ++ks)
            aq[mf][ks] = *(const s16x8*)(qb + (size_t)(q0 + mf * 16 + lc) * D_K +
                                         ks * 32 + quad * 8);

    f32x4 oacc[2][4];
    const f32x4 zero = {0.f, 0.f, 0.f, 0.f};
#pragma unroll
    for (int mf = 0; mf < 2; ++mf)
#pragma unroll
        for (int df = 0; df < 4; ++df) oacc[mf][df] = zero;

    ushort_t* al = asm_ + wave * 32 * 72;   // per-wave attn tile [32][72]

    for (int kt = 0; kt < 32; ++kt) {
        const int j0 = kt * 64;
        // kn b-frags
        s16x8 bk[4][2];
#pragma unroll
        for (int jf = 0; jf < 4; ++jf)
#pragma unroll
            for (int ks = 0; ks < 2; ++ks)
                bk[jf][ks] = *(const s16x8*)(kb + (size_t)(j0 + jf * 16 + lc) * D_K +
                                             ks * 32 + quad * 8);
        __syncthreads();   // prev iteration's aa reads done before overwrite
        // scores -> square -> bf16 -> LDS (C-layout positions)
#pragma unroll
        for (int mf = 0; mf < 2; ++mf)
#pragma unroll
            for (int jf = 0; jf < 4; ++jf) {
                f32x4 s = zero;
#pragma unroll
                for (int ks = 0; ks < 2; ++ks)
                    s = __builtin_amdgcn_mfma_f32_16x16x32_bf16(aq[mf][ks], bk[jf][ks], s, 0, 0, 0);
#pragma unroll
                for (int r = 0; r < 4; ++r)
                    al[(mf * 16 + quad * 4 + r) * 72 + jf * 16 + lc] = f2bf(s[r] * s[r]);
            }
        // v b-frags (vT is (DK,S): K-contiguous for PV)
        s16x8 bv[4][2];
#pragma unroll
        for (int df = 0; df < 4; ++df)
#pragma unroll
            for (int ks = 0; ks < 2; ++ks)
                bv[df][ks] = *(const s16x8*)(vb + (size_t)(df * 16 + lc) * SEQ +
                                             j0 + ks * 32 + quad * 8);
        __syncthreads();   // P writes visible before A-frag reads
        // attn a-frags back from LDS (A-layout)
        s16x8 aa[2][2];
#pragma unroll
        for (int mf = 0; mf < 2; ++mf)
#pragma unroll
            for (int ks = 0; ks < 2; ++ks)
                aa[mf][ks] = *(const s16x8*)(al + (mf * 16 + lc) * 72 + ks * 32 + quad * 8);
        // PV
#pragma unroll
        for (int mf = 0; mf < 2; ++mf)
#pragma unroll
            for (int df = 0; df < 4; ++df)
#pragma unroll
                for (int ks = 0; ks < 2; ++ks)
                    oacc[mf][df] = __builtin_amdgcn_mfma_f32_16x16x32_bf16(
                        aa[mf][ks], bv[df][ks], oacc[mf][df], 0, 0, 0);
    }

    // store to (B,S,D) head-interleaved layout for the output projection
#pragma unroll
    for (int mf = 0; mf < 2; ++mf)
#pragma unroll
        for (int df = 0; df < 4; ++df)
#pragma unroll
            for (int r = 0; r < 4; ++r) {
                int s = q0 + mf * 16 + quad * 4 + r;
                int d = df * 16 + lc;
                attn_out[((size_t)(b * SEQ + s)) * D_MODEL + h * D_K + d] =
                    f2bf(oacc[mf][df][r]);
            }
}

extern "C" void kernel_launch(void* const* d_in, const int* in_sizes, int n_in,
                              void* d_out, int out_size, void* d_ws, size_t ws_size,
                              hipStream_t stream)
{
    // d_in are fp32 per the reference dtypes.
    const float* Qf   = (const float*)d_in[0];
    const float* Kf   = (const float*)d_in[1];
    const float* Vf   = (const float*)d_in[2];
    const float* Wqf  = (const float*)d_in[3];
    const float* Wqbf = (const float*)d_in[4];
    const float* Wkf  = (const float*)d_in[5];
    const float* Wkbf = (const float*)d_in[6];
    const float* Wvf  = (const float*)d_in[7];
    const float* Wvbf = (const float*)d_in[8];
    const float* Wof  = (const float*)d_in[9];
    const float* Wobf = (const float*)d_in[10];

    const size_t NM  = (size_t)M_TOT * D_MODEL;   // 4M elements
    const size_t NW  = (size_t)D_MODEL * D_MODEL; // 1M elements
    const size_t NB  = D_MODEL;                   // 1K elements

    ushort_t* p = (ushort_t*)d_ws;
    ushort_t* Qb  = p;  p += NM;
    ushort_t* Kb  = p;  p += NM;
    ushort_t* Vb  = p;  p += NM;
    ushort_t* Wq  = p;  p += NW;
    ushort_t* Wk  = p;  p += NW;
    ushort_t* Wv  = p;  p += NW;
    ushort_t* Wo  = p;  p += NW;
    ushort_t* bq  = p;  p += NB;
    ushort_t* bk  = p;  p += NB;
    ushort_t* bvv = p;  p += NB;
    ushort_t* bo  = p;  p += NB;
    ushort_t* qn  = p;  p += NM;   // (B,H,S,DK)
    ushort_t* kn  = p;  p += NM;   // (B,H,S,DK)
    ushort_t* vT  = p;  p += NM;   // (B,H,DK,S)
    ushort_t* ao  = p;  p += NM;   // (B,S,D)

    ConvArgs ca;
    ca.src[0] = Qf;   ca.dst[0] = Qb;  ca.n[0] = (int)NM;
    ca.src[1] = Kf;   ca.dst[1] = Kb;  ca.n[1] = (int)NM;
    ca.src[2] = Vf;   ca.dst[2] = Vb;  ca.n[2] = (int)NM;
    ca.src[3] = Wqf;  ca.dst[3] = Wq;  ca.n[3] = (int)NW;
    ca.src[4] = Wkf;  ca.dst[4] = Wk;  ca.n[4] = (int)NW;
    ca.src[5] = Wvf;  ca.dst[5] = Wv;  ca.n[5] = (int)NW;
    ca.src[6] = Wof;  ca.dst[6] = Wo;  ca.n[6] = (int)NW;
    ca.src[7] = Wqbf; ca.dst[7] = bq;  ca.n[7] = (int)NB;
    ca.src[8] = Wkbf; ca.dst[8] = bk;  ca.n[8] = (int)NB;
    ca.src[9] = Wvbf; ca.dst[9] = bvv; ca.n[9] = (int)NB;
    ca.src[10] = Wobf; ca.dst[10] = bo; ca.n[10] = (int)NB;

    dim3 blk(256);
    convert_kernel<<<dim3((unsigned)(NM / (256 * 4)), 11), blk, 0, stream>>>(ca);

    dim3 g1(M_TOT / 128, D_MODEL / 128);            // 32 x 8
    gemm_kernel<1><<<g1, blk, 0, stream>>>(Qb, Wq, bq,  qn, nullptr);
    gemm_kernel<1><<<g1, blk, 0, stream>>>(Kb, Wk, bk,  kn, nullptr);
    gemm_kernel<2><<<g1, blk, 0, stream>>>(Vb, Wv, bvv, vT, nullptr);
    attn_kernel<<<dim3(SEQ / 128, BATCH * N_HEADS), blk, 0, stream>>>(qn, kn, vT, ao);
    gemm_kernel<0><<<g1, blk, 0, stream>>>(ao, Wo, bo, nullptr, (float*)d_out);
}

// Round 3
// 265.378 us; speedup vs baseline: 1.2591x; 1.2591x over previous
//
#include <hip/hip_runtime.h>

// Problem: B=2, S=2048, D_MODEL=1024, H=16, DK=64.
// out = ((l2norm(Q Wq^T) l2norm(K Wk^T)^T)^2 (V Wv^T)) Wo^T   (per head)
// fp32 in/out; internally bf16 MFMA with fp32 accumulation.
//
// Round 3 changes vs round 2:
//  - all GEMM/attn staging via __builtin_amdgcn_global_load_lds width=16
//  - XOR swizzle (phys_chunk = logical ^ (row&7)) on staged tiles: conflict-
//    free ds_read_b128 frag reads (old pattern: 16 lanes -> same 4 banks)
//  - attn: 64-row q-tiles (1024 blocks = 4/CU), per-block k/v staging,
//    per-wave P relayout with wave-local lgkmcnt fence (no block barrier)
//  - QKV projections fused into one grid.z=3 launch (768 blocks = 3/CU)
//  - Wo projection uses BM=64 tiles (512 blocks = 2/CU)

#define D_MODEL 1024
#define N_HEADS 16
#define D_K     64
#define BATCH   2
#define SEQ     2048
#define M_TOT   (BATCH * SEQ)   // 4096

typedef short  s16x8 __attribute__((ext_vector_type(8)));   // 8 bf16 = 4 VGPR
typedef float  f32x4 __attribute__((ext_vector_type(4)));   // MFMA C/D frag
typedef unsigned short ushort_t;
typedef ushort_t us4 __attribute__((ext_vector_type(4)));

__device__ __forceinline__ ushort_t f2bf(float f) {
    union { float f; unsigned int u; } x; x.f = f;
    unsigned int u = x.u;
    return (ushort_t)((u + 0x7fffu + ((u >> 16) & 1u)) >> 16);  // RNE
}
__device__ __forceinline__ float bf2f(ushort_t h) {
    union { unsigned int u; float f; } x; x.u = ((unsigned int)h) << 16;
    return x.f;
}

// async global->LDS, 16B per lane. LDS dest is wave-uniform base + lane*16;
// we pass the per-lane pointer (lane i's value == base + i*16, consistent).
__device__ __forceinline__ void gload_lds16(const ushort_t* g, ushort_t* l) {
    __builtin_amdgcn_global_load_lds(
        (__attribute__((address_space(1))) void*)(ushort_t*)g,
        (__attribute__((address_space(3))) void*)l, 16, 0, 0);
}

// ---------------------------------------------------------------------------
// fp32 -> bf16 conversion, all 11 inputs in one launch (blockIdx.y = tensor).
// ---------------------------------------------------------------------------
struct ConvArgs {
    const float* src[11];
    ushort_t*    dst[11];
    int          n[11];
};

__global__ __launch_bounds__(256) void convert_kernel(ConvArgs a) {
    const int t = blockIdx.y;
    const int i = (blockIdx.x * 256 + threadIdx.x) * 4;
    if (i >= a.n[t]) return;
    const float4 v = *(const float4*)(a.src[t] + i);
    us4 p;
    p[0] = f2bf(v.x); p[1] = f2bf(v.y); p[2] = f2bf(v.z); p[3] = f2bf(v.w);
    *(us4*)(a.dst[t] + i) = p;
}

// ---------------------------------------------------------------------------
// GEMM body: C[m][n] = sum_k A[m][k]*W[n][k] + bias[n]. BM x 128 tile,
// 4 waves 2x2, wave sub-tile (BM/2) x 64. K staged in 64-chunks with
// global_load_lds + XOR swizzle.
// MODE 0: fp32 row-major store   MODE 1: L2-norm -> (B,H,S,DK) bf16
// MODE 2: transpose -> (B,H,DK,S) bf16
// ---------------------------------------------------------------------------
template <int BM, int MODE>
__device__ __forceinline__ void gemm_body(
    ushort_t* __restrict__ smem,
    const ushort_t* __restrict__ A,
    const ushort_t* __restrict__ W,
    const ushort_t* __restrict__ bias,
    ushort_t* __restrict__ out,
    float* __restrict__ outf,
    int bx, int by)
{
    static_assert(BM == 64 || BM == 128, "");
    constexpr int K  = 1024;
    constexpr int MF = BM / 32;          // m-frags per wave
    ushort_t* Ast = smem;                // [BM][64] swizzled
    ushort_t* Bst = smem + BM * 64;      // [128][64] swizzled

    const int t    = threadIdx.x;
    const int wave = t >> 6;
    const int lane = t & 63;
    const int quad = lane >> 4;
    const int lc   = lane & 15;
    const int wm   = wave >> 1;
    const int wn   = wave & 1;
    const int m0   = bx * BM;
    const int n0   = by * 128;

    f32x4 acc[MF][4];
    const f32x4 zero = {0.f, 0.f, 0.f, 0.f};
#pragma unroll
    for (int i = 0; i < MF; ++i)
#pragma unroll
        for (int j = 0; j < 4; ++j) acc[i][j] = zero;

    for (int k0 = 0; k0 < K; k0 += 64) {
#pragma unroll
        for (int c = 0; c < MF * 2; ++c) {           // A tile: BM*64*2B
            int idx = c * 256 + t;
            int row = idx >> 3, phys = idx & 7;
            int col = (phys ^ (row & 7)) * 8;
            gload_lds16(A + (size_t)(m0 + row) * K + k0 + col, Ast + idx * 8);
        }
#pragma unroll
        for (int c = 0; c < 4; ++c) {                // B tile: 128*64*2B
            int idx = c * 256 + t;
            int row = idx >> 3, phys = idx & 7;
            int col = (phys ^ (row & 7)) * 8;
            gload_lds16(W + (size_t)(n0 + row) * K + k0 + col, Bst + idx * 8);
        }
        __syncthreads();   // vmcnt drained by compiler before barrier
#pragma unroll
        for (int ks = 0; ks < 2; ++ks) {
            const int ph = ((ks * 4 + quad) ^ (lc & 7)) * 8;  // swizzled chunk
            s16x8 a[MF], b[4];
#pragma unroll
            for (int i = 0; i < MF; ++i)
                a[i] = *(const s16x8*)(Ast + (wm * (BM / 2) + i * 16 + lc) * 64 + ph);
#pragma unroll
            for (int i = 0; i < 4; ++i)
                b[i] = *(const s16x8*)(Bst + (wn * 64 + i * 16 + lc) * 64 + ph);
#pragma unroll
            for (int mf = 0; mf < MF; ++mf)
#pragma unroll
                for (int nf = 0; nf < 4; ++nf)
                    acc[mf][nf] = __builtin_amdgcn_mfma_f32_16x16x32_bf16(
                        a[mf], b[nf], acc[mf][nf], 0, 0, 0);
        }
        __syncthreads();
    }

    float bv[4];
#pragma unroll
    for (int nf = 0; nf < 4; ++nf) bv[nf] = bf2f(bias[n0 + wn * 64 + nf * 16 + lc]);

    if (MODE == 0) {
#pragma unroll
        for (int mf = 0; mf < MF; ++mf)
#pragma unroll
            for (int nf = 0; nf < 4; ++nf)
#pragma unroll
                for (int r = 0; r < 4; ++r) {
                    int mg = m0 + wm * (BM / 2) + mf * 16 + quad * 4 + r;
                    int ng = n0 + wn * 64 + nf * 16 + lc;
                    outf[(size_t)mg * D_MODEL + ng] = acc[mf][nf][r] + bv[nf];
                }
    } else if (MODE == 1) {
        // wave's 64 cols == one head; row-of-64 lives in 16 lanes x 4 nf regs
#pragma unroll
        for (int mf = 0; mf < MF; ++mf)
#pragma unroll
            for (int r = 0; r < 4; ++r) {
                float ss = 0.f;
#pragma unroll
                for (int nf = 0; nf < 4; ++nf) {
                    float v = acc[mf][nf][r] + bv[nf];
                    acc[mf][nf][r] = v;
                    ss += v * v;
                }
                ss += __shfl_xor(ss, 1);
                ss += __shfl_xor(ss, 2);
                ss += __shfl_xor(ss, 4);
                ss += __shfl_xor(ss, 8);
                float inv = rsqrtf(ss + 1e-8f);
                int mg = m0 + wm * (BM / 2) + mf * 16 + quad * 4 + r;
                int b  = mg >> 11;
                int s  = mg & 2047;
#pragma unroll
                for (int nf = 0; nf < 4; ++nf) {
                    int ng = n0 + wn * 64 + nf * 16 + lc;
                    int h = ng >> 6, d = ng & 63;
                    out[(((size_t)(b * N_HEADS + h)) * SEQ + s) * D_K + d] =
                        f2bf(acc[mf][nf][r] * inv);
                }
            }
    } else {
        // MODE 2: transpose wave's 64(s)x64(d) tile through per-wave LDS
        // region [64 d][stride 72]; wave-local fence (region is private).
        ushort_t* vt = smem + wave * (64 * 72);
#pragma unroll
        for (int mf = 0; mf < 4; ++mf)
#pragma unroll
            for (int nf = 0; nf < 4; ++nf) {
                us4 p;
#pragma unroll
                for (int r = 0; r < 4; ++r) p[r] = f2bf(acc[mf][nf][r] + bv[nf]);
                *(us4*)(vt + (nf * 16 + lc) * 72 + mf * 16 + quad * 4) = p;
            }
        asm volatile("s_waitcnt lgkmcnt(0)" ::: "memory");
#pragma unroll
        for (int r = 0; r < 8; ++r) {
            int d  = r * 8 + (lane >> 3);
            int so = (lane & 7) * 8;
            uint4 val = *(const uint4*)(vt + d * 72 + so);
            int mg = m0 + wm * 64 + so;
            int b  = mg >> 11;
            int s  = mg & 2047;
            int ng = n0 + wn * 64 + d;
            int h = ng >> 6, dh = ng & 63;
            *(uint4*)(out + (((size_t)(b * N_HEADS + h)) * D_K + dh) * SEQ + s) = val;
        }
    }
}

// fused Q/K/V projections: grid.z selects tensor (768 blocks = 3/CU)
__global__ __launch_bounds__(256) void qkv_kernel(
    const ushort_t* __restrict__ Qb, const ushort_t* __restrict__ Kb,
    const ushort_t* __restrict__ Vb,
    const ushort_t* __restrict__ Wq, const ushort_t* __restrict__ Wk,
    const ushort_t* __restrict__ Wv,
    const ushort_t* __restrict__ bq, const ushort_t* __restrict__ bk,
    const ushort_t* __restrict__ bv,
    ushort_t* __restrict__ qn, ushort_t* __restrict__ kn,
    ushort_t* __restrict__ vT)
{
    // staging (128+128)*64 = 16384 words; MODE2 transpose needs 4*64*72 = 18432
    __shared__ __align__(16) ushort_t smem[4 * 64 * 72];
    const int z = blockIdx.z;
    if (z == 0)
        gemm_body<128, 1>(smem, Qb, Wq, bq, qn, nullptr, blockIdx.x, blockIdx.y);
    else if (z == 1)
        gemm_body<128, 1>(smem, Kb, Wk, bk, kn, nullptr, blockIdx.x, blockIdx.y);
    else
        gemm_body<128, 2>(smem, Vb, Wv, bv, vT, nullptr, blockIdx.x, blockIdx.y);
}

// output projection: BM=64 -> 512 blocks = 2/CU
__global__ __launch_bounds__(256) void wo_kernel(
    const ushort_t* __restrict__ A, const ushort_t* __restrict__ W,
    const ushort_t* __restrict__ bias, float* __restrict__ outf)
{
    __shared__ __align__(16) ushort_t smem[(64 + 128) * 64];
    gemm_body<64, 0>(smem, A, W, bias, nullptr, outf, blockIdx.x, blockIdx.y);
}

// ---------------------------------------------------------------------------
// Attention: per (b,h): out = (qn kn^T)^2 v. 64-q-row blocks (1024 blocks),
// 4 waves x 16 q-rows. Per-block k/v staging via global_load_lds (swizzled),
// per-wave P relayout with wave-local lgkmcnt fence.
// ---------------------------------------------------------------------------
__global__ __launch_bounds__(256) void attn_kernel(
    const ushort_t* __restrict__ qn,
    const ushort_t* __restrict__ kn,
    const ushort_t* __restrict__ vT,
    ushort_t* __restrict__ attn_out)
{
    __shared__ __align__(16) ushort_t kst[64 * 64];     // swizzled [j][d]
    __shared__ __align__(16) ushort_t vst[64 * 64];     // swizzled [d][j]
    __shared__ __align__(16) ushort_t pl_all[4 * 16 * 72];

    const int t    = threadIdx.x;
    const int wave = t >> 6;
    const int lane = t & 63;
    const int quad = lane >> 4;
    const int lc   = lane & 15;
    const int qt   = blockIdx.x;       // 0..31
    const int bh   = blockIdx.y;       // 0..31
    const int b    = bh >> 4;
    const int h    = bh & 15;

    const ushort_t* qb = qn + (size_t)bh * SEQ * D_K;
    const ushort_t* kb = kn + (size_t)bh * SEQ * D_K;
    const ushort_t* vb = vT + (size_t)bh * D_K * SEQ;
    const int q0 = qt * 64 + wave * 16;

    // q A-frags, reused across all 32 k-tiles
    s16x8 aq[2];
#pragma unroll
    for (int ks = 0; ks < 2; ++ks)
        aq[ks] = *(const s16x8*)(qb + (size_t)(q0 + lc) * D_K + ks * 32 + quad * 8);

    f32x4 oacc[4];
    const f32x4 zero = {0.f, 0.f, 0.f, 0.f};
#pragma unroll
    for (int df = 0; df < 4; ++df) oacc[df] = zero;

    ushort_t* pl = pl_all + wave * 16 * 72;   // per-wave [16 q][stride 72]

    for (int kt = 0; kt < 32; ++kt) {
        const int j0 = kt * 64;
        // stage k-tile [64 j][64 d] and v-tile [64 d][64 j], XOR-swizzled
#pragma unroll
        for (int c = 0; c < 2; ++c) {
            int idx = c * 256 + t;
            int row = idx >> 3, phys = idx & 7;
            int col = (phys ^ (row & 7)) * 8;
            gload_lds16(kb + (size_t)(j0 + row) * D_K + col, kst + idx * 8);
            gload_lds16(vb + (size_t)row * SEQ + j0 + col, vst + idx * 8);
        }
        __syncthreads();

        // QK^T: S[16 q][64 j]
        const int ph0 = ((0 * 4 + quad) ^ (lc & 7)) * 8;
        const int ph1 = ((1 * 4 + quad) ^ (lc & 7)) * 8;
        s16x8 bk[4][2];
#pragma unroll
        for (int jf = 0; jf < 4; ++jf) {
            bk[jf][0] = *(const s16x8*)(kst + (jf * 16 + lc) * 64 + ph0);
            bk[jf][1] = *(const s16x8*)(kst + (jf * 16 + lc) * 64 + ph1);
        }
        f32x4 s[4];
#pragma unroll
        for (int jf = 0; jf < 4; ++jf) {
            s[jf] = zero;
#pragma unroll
            for (int ks = 0; ks < 2; ++ks)
                s[jf] = __builtin_amdgcn_mfma_f32_16x16x32_bf16(aq[ks], bk[jf][ks], s[jf], 0, 0, 0);
        }
        // square -> bf16 -> per-wave LDS (C-layout positions)
        asm volatile("" ::: "memory");   // keep P writes after prior aa reads
#pragma unroll
        for (int jf = 0; jf < 4; ++jf)
#pragma unroll
            for (int r = 0; r < 4; ++r)
                pl[(quad * 4 + r) * 72 + jf * 16 + lc] = f2bf(s[jf][r] * s[jf][r]);
        // v B-frags
        s16x8 bvf[4][2];
#pragma unroll
        for (int df = 0; df < 4; ++df) {
            bvf[df][0] = *(const s16x8*)(vst + (df * 16 + lc) * 64 + ph0);
            bvf[df][1] = *(const s16x8*)(vst + (df * 16 + lc) * 64 + ph1);
        }
        // wave-local: P writes visible to whole wave (per-wave region, no barrier)
        asm volatile("s_waitcnt lgkmcnt(0)" ::: "memory");
        s16x8 aa[2];
#pragma unroll
        for (int ks = 0; ks < 2; ++ks)
            aa[ks] = *(const s16x8*)(pl + lc * 72 + ks * 32 + quad * 8);
        // PV
#pragma unroll
        for (int df = 0; df < 4; ++df)
#pragma unroll
            for (int ks = 0; ks < 2; ++ks)
                oacc[df] = __builtin_amdgcn_mfma_f32_16x16x32_bf16(
                    aa[ks], bvf[df][ks], oacc[df], 0, 0, 0);
        __syncthreads();   // all frag reads done before next staging overwrite
    }

    // store to (B,S,D) head-interleaved bf16 for the output projection
#pragma unroll
    for (int df = 0; df < 4; ++df)
#pragma unroll
        for (int r = 0; r < 4; ++r) {
            int s = q0 + quad * 4 + r;
            int d = df * 16 + lc;
            attn_out[((size_t)(b * SEQ + s)) * D_MODEL + h * D_K + d] =
                f2bf(oacc[df][r]);
        }
}

extern "C" void kernel_launch(void* const* d_in, const int* in_sizes, int n_in,
                              void* d_out, int out_size, void* d_ws, size_t ws_size,
                              hipStream_t stream)
{
    const float* Qf   = (const float*)d_in[0];
    const float* Kf   = (const float*)d_in[1];
    const float* Vf   = (const float*)d_in[2];
    const float* Wqf  = (const float*)d_in[3];
    const float* Wqbf = (const float*)d_in[4];
    const float* Wkf  = (const float*)d_in[5];
    const float* Wkbf = (const float*)d_in[6];
    const float* Wvf  = (const float*)d_in[7];
    const float* Wvbf = (const float*)d_in[8];
    const float* Wof  = (const float*)d_in[9];
    const float* Wobf = (const float*)d_in[10];

    const size_t NM = (size_t)M_TOT * D_MODEL;
    const size_t NW = (size_t)D_MODEL * D_MODEL;
    const size_t NB = D_MODEL;

    ushort_t* p = (ushort_t*)d_ws;
    ushort_t* Qb  = p;  p += NM;
    ushort_t* Kb  = p;  p += NM;
    ushort_t* Vb  = p;  p += NM;
    ushort_t* Wq  = p;  p += NW;
    ushort_t* Wk  = p;  p += NW;
    ushort_t* Wv  = p;  p += NW;
    ushort_t* Wo  = p;  p += NW;
    ushort_t* bq  = p;  p += NB;
    ushort_t* bk  = p;  p += NB;
    ushort_t* bvv = p;  p += NB;
    ushort_t* bo  = p;  p += NB;
    ushort_t* qn  = p;  p += NM;   // (B,H,S,DK)
    ushort_t* kn  = p;  p += NM;   // (B,H,S,DK)
    ushort_t* vT  = p;  p += NM;   // (B,H,DK,S)
    ushort_t* ao  = p;  p += NM;   // (B,S,D)

    ConvArgs ca;
    ca.src[0] = Qf;   ca.dst[0] = Qb;  ca.n[0] = (int)NM;
    ca.src[1] = Kf;   ca.dst[1] = Kb;  ca.n[1] = (int)NM;
    ca.src[2] = Vf;   ca.dst[2] = Vb;  ca.n[2] = (int)NM;
    ca.src[3] = Wqf;  ca.dst[3] = Wq;  ca.n[3] = (int)NW;
    ca.src[4] = Wkf;  ca.dst[4] = Wk;  ca.n[4] = (int)NW;
    ca.src[5] = Wvf;  ca.dst[5] = Wv;  ca.n[5] = (int)NW;
    ca.src[6] = Wof;  ca.dst[6] = Wo;  ca.n[6] = (int)NW;
    ca.src[7] = Wqbf; ca.dst[7] = bq;  ca.n[7] = (int)NB;
    ca.src[8] = Wkbf; ca.dst[8] = bk;  ca.n[8] = (int)NB;
    ca.src[9] = Wvbf; ca.dst[9] = bvv; ca.n[9] = (int)NB;
    ca.src[10] = Wobf; ca.dst[10] = bo; ca.n[10] = (int)NB;

    dim3 blk(256);
    convert_kernel<<<dim3((unsigned)(NM / (256 * 4)), 11), blk, 0, stream>>>(ca);

    qkv_kernel<<<dim3(M_TOT / 128, D_MODEL / 128, 3), blk, 0, stream>>>(
        Qb, Kb, Vb, Wq, Wk, Wv, bq, bk, bvv, qn, kn, vT);
    attn_kernel<<<dim3(SEQ / 64, BATCH * N_HEADS), blk, 0, stream>>>(qn, kn, vT, ao);
    wo_kernel<<<dim3(M_TOT / 64, D_MODEL / 128), blk, 0, stream>>>(
        ao, Wo, bo, (float*)d_out);
}

// Round 4
// 254.301 us; speedup vs baseline: 1.3139x; 1.0436x over previous
//
#include <hip/hip_runtime.h>

// Problem: B=2, S=2048, D_MODEL=1024, H=16, DK=64.
// out = ((l2norm(Q Wq^T) l2norm(K Wk^T)^T)^2 (V Wv^T)) Wo^T   (per head)
// fp32 in/out; internally bf16 MFMA with fp32 accumulation.
//
// Round 4 change vs round 3:
//  - FIX: A-tile staging loop ran c < MF*2 (2x the tile size), reading rows
//    past the m-tile (OOB on the last block) and writing junk over Bst that
//    only worked because B's DMA landed later. Correct count is c < MF
//    (BM*64 elems / (256 threads * 8 elems/lane) == MF). Cuts per-iter DMA
//    from 12 to 8 issues (qkv) and removes the OOB reads.

#define D_MODEL 1024
#define N_HEADS 16
#define D_K     64
#define BATCH   2
#define SEQ     2048
#define M_TOT   (BATCH * SEQ)   // 4096

typedef short  s16x8 __attribute__((ext_vector_type(8)));   // 8 bf16 = 4 VGPR
typedef float  f32x4 __attribute__((ext_vector_type(4)));   // MFMA C/D frag
typedef unsigned short ushort_t;
typedef ushort_t us4 __attribute__((ext_vector_type(4)));

__device__ __forceinline__ ushort_t f2bf(float f) {
    union { float f; unsigned int u; } x; x.f = f;
    unsigned int u = x.u;
    return (ushort_t)((u + 0x7fffu + ((u >> 16) & 1u)) >> 16);  // RNE
}
__device__ __forceinline__ float bf2f(ushort_t h) {
    union { unsigned int u; float f; } x; x.u = ((unsigned int)h) << 16;
    return x.f;
}

// async global->LDS, 16B per lane. LDS dest is wave-uniform base + lane*16;
// we pass the per-lane pointer (lane i's value == base + i*16, consistent).
__device__ __forceinline__ void gload_lds16(const ushort_t* g, ushort_t* l) {
    __builtin_amdgcn_global_load_lds(
        (__attribute__((address_space(1))) void*)(ushort_t*)g,
        (__attribute__((address_space(3))) void*)l, 16, 0, 0);
}

// ---------------------------------------------------------------------------
// fp32 -> bf16 conversion, all 11 inputs in one launch (blockIdx.y = tensor).
// ---------------------------------------------------------------------------
struct ConvArgs {
    const float* src[11];
    ushort_t*    dst[11];
    int          n[11];
};

__global__ __launch_bounds__(256) void convert_kernel(ConvArgs a) {
    const int t = blockIdx.y;
    const int i = (blockIdx.x * 256 + threadIdx.x) * 4;
    if (i >= a.n[t]) return;
    const float4 v = *(const float4*)(a.src[t] + i);
    us4 p;
    p[0] = f2bf(v.x); p[1] = f2bf(v.y); p[2] = f2bf(v.z); p[3] = f2bf(v.w);
    *(us4*)(a.dst[t] + i) = p;
}

// ---------------------------------------------------------------------------
// GEMM body: C[m][n] = sum_k A[m][k]*W[n][k] + bias[n]. BM x 128 tile,
// 4 waves 2x2, wave sub-tile (BM/2) x 64. K staged in 64-chunks with
// global_load_lds + XOR swizzle.
// MODE 0: fp32 row-major store   MODE 1: L2-norm -> (B,H,S,DK) bf16
// MODE 2: transpose -> (B,H,DK,S) bf16
// ---------------------------------------------------------------------------
template <int BM, int MODE>
__device__ __forceinline__ void gemm_body(
    ushort_t* __restrict__ smem,
    const ushort_t* __restrict__ A,
    const ushort_t* __restrict__ W,
    const ushort_t* __restrict__ bias,
    ushort_t* __restrict__ out,
    float* __restrict__ outf,
    int bx, int by)
{
    static_assert(BM == 64 || BM == 128, "");
    constexpr int K  = 1024;
    constexpr int MF = BM / 32;          // m-frags per wave; also A staging iters
    ushort_t* Ast = smem;                // [BM][64] swizzled
    ushort_t* Bst = smem + BM * 64;      // [128][64] swizzled

    const int t    = threadIdx.x;
    const int wave = t >> 6;
    const int lane = t & 63;
    const int quad = lane >> 4;
    const int lc   = lane & 15;
    const int wm   = wave >> 1;
    const int wn   = wave & 1;
    const int m0   = bx * BM;
    const int n0   = by * 128;

    f32x4 acc[MF][4];
    const f32x4 zero = {0.f, 0.f, 0.f, 0.f};
#pragma unroll
    for (int i = 0; i < MF; ++i)
#pragma unroll
        for (int j = 0; j < 4; ++j) acc[i][j] = zero;

    for (int k0 = 0; k0 < K; k0 += 64) {
        // A tile: BM*64 elems = MF * (256 lanes * 8 elems)
#pragma unroll
        for (int c = 0; c < MF; ++c) {
            int idx = c * 256 + t;
            int row = idx >> 3, phys = idx & 7;
            int col = (phys ^ (row & 7)) * 8;
            gload_lds16(A + (size_t)(m0 + row) * K + k0 + col, Ast + idx * 8);
        }
        // B tile: 128*64 elems = 4 * (256 * 8)
#pragma unroll
        for (int c = 0; c < 4; ++c) {
            int idx = c * 256 + t;
            int row = idx >> 3, phys = idx & 7;
            int col = (phys ^ (row & 7)) * 8;
            gload_lds16(W + (size_t)(n0 + row) * K + k0 + col, Bst + idx * 8);
        }
        __syncthreads();   // vmcnt drained by compiler before barrier
#pragma unroll
        for (int ks = 0; ks < 2; ++ks) {
            const int ph = ((ks * 4 + quad) ^ (lc & 7)) * 8;  // swizzled chunk
            s16x8 a[MF], b[4];
#pragma unroll
            for (int i = 0; i < MF; ++i)
                a[i] = *(const s16x8*)(Ast + (wm * (BM / 2) + i * 16 + lc) * 64 + ph);
#pragma unroll
            for (int i = 0; i < 4; ++i)
                b[i] = *(const s16x8*)(Bst + (wn * 64 + i * 16 + lc) * 64 + ph);
#pragma unroll
            for (int mf = 0; mf < MF; ++mf)
#pragma unroll
                for (int nf = 0; nf < 4; ++nf)
                    acc[mf][nf] = __builtin_amdgcn_mfma_f32_16x16x32_bf16(
                        a[mf], b[nf], acc[mf][nf], 0, 0, 0);
        }
        __syncthreads();
    }

    float bv[4];
#pragma unroll
    for (int nf = 0; nf < 4; ++nf) bv[nf] = bf2f(bias[n0 + wn * 64 + nf * 16 + lc]);

    if (MODE == 0) {
#pragma unroll
        for (int mf = 0; mf < MF; ++mf)
#pragma unroll
            for (int nf = 0; nf < 4; ++nf)
#pragma unroll
                for (int r = 0; r < 4; ++r) {
                    int mg = m0 + wm * (BM / 2) + mf * 16 + quad * 4 + r;
                    int ng = n0 + wn * 64 + nf * 16 + lc;
                    outf[(size_t)mg * D_MODEL + ng] = acc[mf][nf][r] + bv[nf];
                }
    } else if (MODE == 1) {
        // wave's 64 cols == one head; row-of-64 lives in 16 lanes x 4 nf regs
#pragma unroll
        for (int mf = 0; mf < MF; ++mf)
#pragma unroll
            for (int r = 0; r < 4; ++r) {
                float ss = 0.f;
#pragma unroll
                for (int nf = 0; nf < 4; ++nf) {
                    float v = acc[mf][nf][r] + bv[nf];
                    acc[mf][nf][r] = v;
                    ss += v * v;
                }
                ss += __shfl_xor(ss, 1);
                ss += __shfl_xor(ss, 2);
                ss += __shfl_xor(ss, 4);
                ss += __shfl_xor(ss, 8);
                float inv = rsqrtf(ss + 1e-8f);
                int mg = m0 + wm * (BM / 2) + mf * 16 + quad * 4 + r;
                int b  = mg >> 11;
                int s  = mg & 2047;
#pragma unroll
                for (int nf = 0; nf < 4; ++nf) {
                    int ng = n0 + wn * 64 + nf * 16 + lc;
                    int h = ng >> 6, d = ng & 63;
                    out[(((size_t)(b * N_HEADS + h)) * SEQ + s) * D_K + d] =
                        f2bf(acc[mf][nf][r] * inv);
                }
            }
    } else {
        // MODE 2: transpose wave's 64(s)x64(d) tile through per-wave LDS
        // region [64 d][stride 72]; wave-local fence (region is private).
        ushort_t* vt = smem + wave * (64 * 72);
#pragma unroll
        for (int mf = 0; mf < 4; ++mf)
#pragma unroll
            for (int nf = 0; nf < 4; ++nf) {
                us4 p;
#pragma unroll
                for (int r = 0; r < 4; ++r) p[r] = f2bf(acc[mf][nf][r] + bv[nf]);
                *(us4*)(vt + (nf * 16 + lc) * 72 + mf * 16 + quad * 4) = p;
            }
        asm volatile("s_waitcnt lgkmcnt(0)" ::: "memory");
#pragma unroll
        for (int r = 0; r < 8; ++r) {
            int d  = r * 8 + (lane >> 3);
            int so = (lane & 7) * 8;
            uint4 val = *(const uint4*)(vt + d * 72 + so);
            int mg = m0 + wm * 64 + so;
            int b  = mg >> 11;
            int s  = mg & 2047;
            int ng = n0 + wn * 64 + d;
            int h = ng >> 6, dh = ng & 63;
            *(uint4*)(out + (((size_t)(b * N_HEADS + h)) * D_K + dh) * SEQ + s) = val;
        }
    }
}

// fused Q/K/V projections: grid.z selects tensor (768 blocks = 3/CU)
__global__ __launch_bounds__(256) void qkv_kernel(
    const ushort_t* __restrict__ Qb, const ushort_t* __restrict__ Kb,
    const ushort_t* __restrict__ Vb,
    const ushort_t* __restrict__ Wq, const ushort_t* __restrict__ Wk,
    const ushort_t* __restrict__ Wv,
    const ushort_t* __restrict__ bq, const ushort_t* __restrict__ bk,
    const ushort_t* __restrict__ bv,
    ushort_t* __restrict__ qn, ushort_t* __restrict__ kn,
    ushort_t* __restrict__ vT)
{
    // staging (128+128)*64 = 16384 words; MODE2 transpose needs 4*64*72 = 18432
    __shared__ __align__(16) ushort_t smem[4 * 64 * 72];
    const int z = blockIdx.z;
    if (z == 0)
        gemm_body<128, 1>(smem, Qb, Wq, bq, qn, nullptr, blockIdx.x, blockIdx.y);
    else if (z == 1)
        gemm_body<128, 1>(smem, Kb, Wk, bk, kn, nullptr, blockIdx.x, blockIdx.y);
    else
        gemm_body<128, 2>(smem, Vb, Wv, bv, vT, nullptr, blockIdx.x, blockIdx.y);
}

// output projection: BM=64 -> 512 blocks = 2/CU
__global__ __launch_bounds__(256) void wo_kernel(
    const ushort_t* __restrict__ A, const ushort_t* __restrict__ W,
    const ushort_t* __restrict__ bias, float* __restrict__ outf)
{
    __shared__ __align__(16) ushort_t smem[(64 + 128) * 64];
    gemm_body<64, 0>(smem, A, W, bias, nullptr, outf, blockIdx.x, blockIdx.y);
}

// ---------------------------------------------------------------------------
// Attention: per (b,h): out = (qn kn^T)^2 v. 64-q-row blocks (1024 blocks),
// 4 waves x 16 q-rows. Per-block k/v staging via global_load_lds (swizzled),
// per-wave P relayout with wave-local lgkmcnt fence.
// ---------------------------------------------------------------------------
__global__ __launch_bounds__(256) void attn_kernel(
    const ushort_t* __restrict__ qn,
    const ushort_t* __restrict__ kn,
    const ushort_t* __restrict__ vT,
    ushort_t* __restrict__ attn_out)
{
    __shared__ __align__(16) ushort_t kst[64 * 64];     // swizzled [j][d]
    __shared__ __align__(16) ushort_t vst[64 * 64];     // swizzled [d][j]
    __shared__ __align__(16) ushort_t pl_all[4 * 16 * 72];

    const int t    = threadIdx.x;
    const int wave = t >> 6;
    const int lane = t & 63;
    const int quad = lane >> 4;
    const int lc   = lane & 15;
    const int qt   = blockIdx.x;       // 0..31
    const int bh   = blockIdx.y;       // 0..31
    const int b    = bh >> 4;
    const int h    = bh & 15;

    const ushort_t* qb = qn + (size_t)bh * SEQ * D_K;
    const ushort_t* kb = kn + (size_t)bh * SEQ * D_K;
    const ushort_t* vb = vT + (size_t)bh * D_K * SEQ;
    const int q0 = qt * 64 + wave * 16;

    // q A-frags, reused across all 32 k-tiles
    s16x8 aq[2];
#pragma unroll
    for (int ks = 0; ks < 2; ++ks)
        aq[ks] = *(const s16x8*)(qb + (size_t)(q0 + lc) * D_K + ks * 32 + quad * 8);

    f32x4 oacc[4];
    const f32x4 zero = {0.f, 0.f, 0.f, 0.f};
#pragma unroll
    for (int df = 0; df < 4; ++df) oacc[df] = zero;

    ushort_t* pl = pl_all + wave * 16 * 72;   // per-wave [16 q][stride 72]

    for (int kt = 0; kt < 32; ++kt) {
        const int j0 = kt * 64;
        // stage k-tile [64 j][64 d] and v-tile [64 d][64 j], XOR-swizzled
#pragma unroll
        for (int c = 0; c < 2; ++c) {
            int idx = c * 256 + t;
            int row = idx >> 3, phys = idx & 7;
            int col = (phys ^ (row & 7)) * 8;
            gload_lds16(kb + (size_t)(j0 + row) * D_K + col, kst + idx * 8);
            gload_lds16(vb + (size_t)row * SEQ + j0 + col, vst + idx * 8);
        }
        __syncthreads();

        // QK^T: S[16 q][64 j]
        const int ph0 = ((0 * 4 + quad) ^ (lc & 7)) * 8;
        const int ph1 = ((1 * 4 + quad) ^ (lc & 7)) * 8;
        s16x8 bk[4][2];
#pragma unroll
        for (int jf = 0; jf < 4; ++jf) {
            bk[jf][0] = *(const s16x8*)(kst + (jf * 16 + lc) * 64 + ph0);
            bk[jf][1] = *(const s16x8*)(kst + (jf * 16 + lc) * 64 + ph1);
        }
        f32x4 s[4];
#pragma unroll
        for (int jf = 0; jf < 4; ++jf) {
            s[jf] = zero;
#pragma unroll
            for (int ks = 0; ks < 2; ++ks)
                s[jf] = __builtin_amdgcn_mfma_f32_16x16x32_bf16(aq[ks], bk[jf][ks], s[jf], 0, 0, 0);
        }
        // square -> bf16 -> per-wave LDS (C-layout positions)
        asm volatile("" ::: "memory");   // keep P writes after prior aa reads
#pragma unroll
        for (int jf = 0; jf < 4; ++jf)
#pragma unroll
            for (int r = 0; r < 4; ++r)
                pl[(quad * 4 + r) * 72 + jf * 16 + lc] = f2bf(s[jf][r] * s[jf][r]);
        // v B-frags
        s16x8 bvf[4][2];
#pragma unroll
        for (int df = 0; df < 4; ++df) {
            bvf[df][0] = *(const s16x8*)(vst + (df * 16 + lc) * 64 + ph0);
            bvf[df][1] = *(const s16x8*)(vst + (df * 16 + lc) * 64 + ph1);
        }
        // wave-local: P writes visible to whole wave (per-wave region, no barrier)
        asm volatile("s_waitcnt lgkmcnt(0)" ::: "memory");
        s16x8 aa[2];
#pragma unroll
        for (int ks = 0; ks < 2; ++ks)
            aa[ks] = *(const s16x8*)(pl + lc * 72 + ks * 32 + quad * 8);
        // PV
#pragma unroll
        for (int df = 0; df < 4; ++df)
#pragma unroll
            for (int ks = 0; ks < 2; ++ks)
                oacc[df] = __builtin_amdgcn_mfma_f32_16x16x32_bf16(
                    aa[ks], bvf[df][ks], oacc[df], 0, 0, 0);
        __syncthreads();   // all frag reads done before next staging overwrite
    }

    // store to (B,S,D) head-interleaved bf16 for the output projection
#pragma unroll
    for (int df = 0; df < 4; ++df)
#pragma unroll
        for (int r = 0; r < 4; ++r) {
            int s = q0 + quad * 4 + r;
            int d = df * 16 + lc;
            attn_out[((size_t)(b * SEQ + s)) * D_MODEL + h * D_K + d] =
                f2bf(oacc[df][r]);
        }
}

extern "C" void kernel_launch(void* const* d_in, const int* in_sizes, int n_in,
                              void* d_out, int out_size, void* d_ws, size_t ws_size,
                              hipStream_t stream)
{
    const float* Qf   = (const float*)d_in[0];
    const float* Kf   = (const float*)d_in[1];
    const float* Vf   = (const float*)d_in[2];
    const float* Wqf  = (const float*)d_in[3];
    const float* Wqbf = (const float*)d_in[4];
    const float* Wkf  = (const float*)d_in[5];
    const float* Wkbf = (const float*)d_in[6];
    const float* Wvf  = (const float*)d_in[7];
    const float* Wvbf = (const float*)d_in[8];
    const float* Wof  = (const float*)d_in[9];
    const float* Wobf = (const float*)d_in[10];

    const size_t NM = (size_t)M_TOT * D_MODEL;
    const size_t NW = (size_t)D_MODEL * D_MODEL;
    const size_t NB = D_MODEL;

    ushort_t* p = (ushort_t*)d_ws;
    ushort_t* Qb  = p;  p += NM;
    ushort_t* Kb  = p;  p += NM;
    ushort_t* Vb  = p;  p += NM;
    ushort_t* Wq  = p;  p += NW;
    ushort_t* Wk  = p;  p += NW;
    ushort_t* Wv  = p;  p += NW;
    ushort_t* Wo  = p;  p += NW;
    ushort_t* bq  = p;  p += NB;
    ushort_t* bk  = p;  p += NB;
    ushort_t* bvv = p;  p += NB;
    ushort_t* bo  = p;  p += NB;
    ushort_t* qn  = p;  p += NM;   // (B,H,S,DK)
    ushort_t* kn  = p;  p += NM;   // (B,H,S,DK)
    ushort_t* vT  = p;  p += NM;   // (B,H,DK,S)
    ushort_t* ao  = p;  p += NM;   // (B,S,D)

    ConvArgs ca;
    ca.src[0] = Qf;   ca.dst[0] = Qb;  ca.n[0] = (int)NM;
    ca.src[1] = Kf;   ca.dst[1] = Kb;  ca.n[1] = (int)NM;
    ca.src[2] = Vf;   ca.dst[2] = Vb;  ca.n[2] = (int)NM;
    ca.src[3] = Wqf;  ca.dst[3] = Wq;  ca.n[3] = (int)NW;
    ca.src[4] = Wkf;  ca.dst[4] = Wk;  ca.n[4] = (int)NW;
    ca.src[5] = Wvf;  ca.dst[5] = Wv;  ca.n[5] = (int)NW;
    ca.src[6] = Wof;  ca.dst[6] = Wo;  ca.n[6] = (int)NW;
    ca.src[7] = Wqbf; ca.dst[7] = bq;  ca.n[7] = (int)NB;
    ca.src[8] = Wkbf; ca.dst[8] = bk;  ca.n[8] = (int)NB;
    ca.src[9] = Wvbf; ca.dst[9] = bvv; ca.n[9] = (int)NB;
    ca.src[10] = Wobf; ca.dst[10] = bo; ca.n[10] = (int)NB;

    dim3 blk(256);
    convert_kernel<<<dim3((unsigned)(NM / (256 * 4)), 11), blk, 0, stream>>>(ca);

    qkv_kernel<<<dim3(M_TOT / 128, D_MODEL / 128, 3), blk, 0, stream>>>(
        Qb, Kb, Vb, Wq, Wk, Wv, bq, bk, bvv, qn, kn, vT);
    attn_kernel<<<dim3(SEQ / 64, BATCH * N_HEADS), blk, 0, stream>>>(qn, kn, vT, ao);
    wo_kernel<<<dim3(M_TOT / 64, D_MODEL / 128), blk, 0, stream>>>(
        ao, Wo, bo, (float*)d_out);
}

// Round 5
// 238.159 us; speedup vs baseline: 1.4030x; 1.0678x over previous
//
#include <hip/hip_runtime.h>

// Problem: B=2, S=2048, D_MODEL=1024, H=16, DK=64.
// out = ((l2norm(Q Wq^T) l2norm(K Wk^T)^T)^2 (V Wv^T)) Wo^T   (per head)
// fp32 in/out; internally bf16 MFMA with fp32 accumulation.
//
// Round 5 change vs round 4:
//  - K-loops restructured as 2-deep DMA pipelines with raw s_barrier +
//    explicit s_waitcnt vmcnt(N) (m139/s02 pattern). Tile k+2's
//    global_load_lds are issued at the end of iter k; top-of-iter wait is
//    vmcnt(PER_TILE) so the next tile's DMAs stay in flight across a full
//    iteration. __syncthreads (which drains vmcnt(0), defeating prefetch)
//    is eliminated from all hot loops. R4 evidence: vmcnt-drain latency
//    bound (MfmaUtil 9.9%, accidental-L2-prefetch made R3 faster).
//  - LDS double buffers: qkv 64 KB (2 blk/CU), attn 41 KB (3), wo 48 KB (3).

#define D_MODEL 1024
#define N_HEADS 16
#define D_K     64
#define BATCH   2
#define SEQ     2048
#define M_TOT   (BATCH * SEQ)   // 4096

typedef short  s16x8 __attribute__((ext_vector_type(8)));   // 8 bf16 = 4 VGPR
typedef float  f32x4 __attribute__((ext_vector_type(4)));   // MFMA C/D frag
typedef unsigned short ushort_t;
typedef ushort_t us4 __attribute__((ext_vector_type(4)));

__device__ __forceinline__ ushort_t f2bf(float f) {
    union { float f; unsigned int u; } x; x.f = f;
    unsigned int u = x.u;
    return (ushort_t)((u + 0x7fffu + ((u >> 16) & 1u)) >> 16);  // RNE
}
__device__ __forceinline__ float bf2f(ushort_t h) {
    union { unsigned int u; float f; } x; x.u = ((unsigned int)h) << 16;
    return x.f;
}

// async global->LDS, 16B per lane (lane i's lds ptr == wave base + i*16).
__device__ __forceinline__ void gload_lds16(const ushort_t* g, ushort_t* l) {
    __builtin_amdgcn_global_load_lds(
        (__attribute__((address_space(1))) void*)(ushort_t*)g,
        (__attribute__((address_space(3))) void*)l, 16, 0, 0);
}

#define WAIT_VM(n)  asm volatile("s_waitcnt vmcnt(" #n ")" ::: "memory")
#define WAIT_LGKM0  asm volatile("s_waitcnt lgkmcnt(0)" ::: "memory")
#define BARRIER     asm volatile("s_barrier" ::: "memory")

// ---------------------------------------------------------------------------
// fp32 -> bf16 conversion, all 11 inputs in one launch (blockIdx.y = tensor).
// ---------------------------------------------------------------------------
struct ConvArgs {
    const float* src[11];
    ushort_t*    dst[11];
    int          n[11];
};

__global__ __launch_bounds__(256) void convert_kernel(ConvArgs a) {
    const int t = blockIdx.y;
    const int i = (blockIdx.x * 256 + threadIdx.x) * 4;
    if (i >= a.n[t]) return;
    const float4 v = *(const float4*)(a.src[t] + i);
    us4 p;
    p[0] = f2bf(v.x); p[1] = f2bf(v.y); p[2] = f2bf(v.z); p[3] = f2bf(v.w);
    *(us4*)(a.dst[t] + i) = p;
}

// ---------------------------------------------------------------------------
// GEMM body: C[m][n] = sum_k A[m][k]*W[n][k] + bias[n]. BM x 128 tile,
// 4 waves 2x2. 2-deep DMA pipeline, BK=64.
// Per-wave DMAs per tile: MF (A) + 4 (B).  BM=128 -> 8, BM=64 -> 6.
// MODE 0: fp32 row-major store   MODE 1: L2-norm -> (B,H,S,DK) bf16
// MODE 2: transpose -> (B,H,DK,S) bf16
// ---------------------------------------------------------------------------
template <int BM, int MODE>
__device__ __forceinline__ void gemm_body(
    ushort_t* __restrict__ smem,
    const ushort_t* __restrict__ A,
    const ushort_t* __restrict__ W,
    const ushort_t* __restrict__ bias,
    ushort_t* __restrict__ out,
    float* __restrict__ outf,
    int bx, int by)
{
    static_assert(BM == 64 || BM == 128, "");
    constexpr int K    = 1024;
    constexpr int MF   = BM / 32;
    constexpr int BUFW = (BM + 128) * 64;   // words per LDS buffer
    constexpr int NIT  = K / 64;            // 16

    const int t    = threadIdx.x;
    const int wave = t >> 6;
    const int lane = t & 63;
    const int quad = lane >> 4;
    const int lc   = lane & 15;
    const int wm   = wave >> 1;
    const int wn   = wave & 1;
    const int m0   = bx * BM;
    const int n0   = by * 128;

    f32x4 acc[MF][4];
    const f32x4 zero = {0.f, 0.f, 0.f, 0.f};
#pragma unroll
    for (int i = 0; i < MF; ++i)
#pragma unroll
        for (int j = 0; j < 4; ++j) acc[i][j] = zero;

    auto stage = [&](int buf, int k0) {
        ushort_t* Ast = smem + buf * BUFW;
        ushort_t* Bst = Ast + BM * 64;
#pragma unroll
        for (int c = 0; c < MF; ++c) {
            int idx = c * 256 + t;
            int row = idx >> 3, phys = idx & 7;
            int col = (phys ^ (row & 7)) * 8;
            gload_lds16(A + (size_t)(m0 + row) * K + k0 + col, Ast + idx * 8);
        }
#pragma unroll
        for (int c = 0; c < 4; ++c) {
            int idx = c * 256 + t;
            int row = idx >> 3, phys = idx & 7;
            int col = (phys ^ (row & 7)) * 8;
            gload_lds16(W + (size_t)(n0 + row) * K + k0 + col, Bst + idx * 8);
        }
    };
    auto comp = [&](int buf) {
        ushort_t* Ast = smem + buf * BUFW;
        ushort_t* Bst = Ast + BM * 64;
#pragma unroll
        for (int ks = 0; ks < 2; ++ks) {
            const int ph = ((ks * 4 + quad) ^ (lc & 7)) * 8;
            s16x8 a[MF], b[4];
#pragma unroll
            for (int i = 0; i < MF; ++i)
                a[i] = *(const s16x8*)(Ast + (wm * (BM / 2) + i * 16 + lc) * 64 + ph);
#pragma unroll
            for (int i = 0; i < 4; ++i)
                b[i] = *(const s16x8*)(Bst + (wn * 64 + i * 16 + lc) * 64 + ph);
#pragma unroll
            for (int mf = 0; mf < MF; ++mf)
#pragma unroll
                for (int nf = 0; nf < 4; ++nf)
                    acc[mf][nf] = __builtin_amdgcn_mfma_f32_16x16x32_bf16(
                        a[mf], b[nf], acc[mf][nf], 0, 0, 0);
        }
    };

    stage(0, 0);
    stage(1, 64);
    // steady state: iters 0..NIT-3, each issues tile it+2 into buf(it&1)
    for (int it = 0; it < NIT - 2; ++it) {
        if constexpr (BM == 128) WAIT_VM(8); else WAIT_VM(6);
        BARRIER;                  // tile `it` fully landed (all waves waited)
        comp(it & 1);
        WAIT_LGKM0;               // my frag reads are in registers
        BARRIER;                  // all waves done reading buf(it&1)
        stage(it & 1, (it + 2) * 64);
    }
    // iter NIT-2 (buf 0): tile NIT-1 still in flight
    if constexpr (BM == 128) WAIT_VM(8); else WAIT_VM(6);
    BARRIER;
    comp((NIT - 2) & 1);
    // iter NIT-1 (buf 1): drain everything
    WAIT_VM(0);
    BARRIER;
    comp((NIT - 1) & 1);

    float bv[4];
#pragma unroll
    for (int nf = 0; nf < 4; ++nf) bv[nf] = bf2f(bias[n0 + wn * 64 + nf * 16 + lc]);

    if (MODE == 0) {
#pragma unroll
        for (int mf = 0; mf < MF; ++mf)
#pragma unroll
            for (int nf = 0; nf < 4; ++nf)
#pragma unroll
                for (int r = 0; r < 4; ++r) {
                    int mg = m0 + wm * (BM / 2) + mf * 16 + quad * 4 + r;
                    int ng = n0 + wn * 64 + nf * 16 + lc;
                    outf[(size_t)mg * D_MODEL + ng] = acc[mf][nf][r] + bv[nf];
                }
    } else if (MODE == 1) {
        // wave's 64 cols == one head; row-of-64 lives in 16 lanes x 4 nf regs
#pragma unroll
        for (int mf = 0; mf < MF; ++mf)
#pragma unroll
            for (int r = 0; r < 4; ++r) {
                float ss = 0.f;
#pragma unroll
                for (int nf = 0; nf < 4; ++nf) {
                    float v = acc[mf][nf][r] + bv[nf];
                    acc[mf][nf][r] = v;
                    ss += v * v;
                }
                ss += __shfl_xor(ss, 1);
                ss += __shfl_xor(ss, 2);
                ss += __shfl_xor(ss, 4);
                ss += __shfl_xor(ss, 8);
                float inv = rsqrtf(ss + 1e-8f);
                int mg = m0 + wm * (BM / 2) + mf * 16 + quad * 4 + r;
                int b  = mg >> 11;
                int s  = mg & 2047;
#pragma unroll
                for (int nf = 0; nf < 4; ++nf) {
                    int ng = n0 + wn * 64 + nf * 16 + lc;
                    int h = ng >> 6, d = ng & 63;
                    out[(((size_t)(b * N_HEADS + h)) * SEQ + s) * D_K + d] =
                        f2bf(acc[mf][nf][r] * inv);
                }
            }
    } else {
        // MODE 2: transpose wave's 64(s)x64(d) tile through per-wave LDS
        // region [64 d][stride 72]. Wave regions overlap buf1 which other
        // waves may still be reading in comp -> block barrier first.
        __syncthreads();
        ushort_t* vt = smem + wave * (64 * 72);
#pragma unroll
        for (int mf = 0; mf < 4; ++mf)
#pragma unroll
            for (int nf = 0; nf < 4; ++nf) {
                us4 p;
#pragma unroll
                for (int r = 0; r < 4; ++r) p[r] = f2bf(acc[mf][nf][r] + bv[nf]);
                *(us4*)(vt + (nf * 16 + lc) * 72 + mf * 16 + quad * 4) = p;
            }
        WAIT_LGKM0;   // wave-private region: wave-local fence suffices
#pragma unroll
        for (int r = 0; r < 8; ++r) {
            int d  = r * 8 + (lane >> 3);
            int so = (lane & 7) * 8;
            uint4 val = *(const uint4*)(vt + d * 72 + so);
            int mg = m0 + wm * 64 + so;
            int b  = mg >> 11;
            int s  = mg & 2047;
            int ng = n0 + wn * 64 + d;
            int h = ng >> 6, dh = ng & 63;
            *(uint4*)(out + (((size_t)(b * N_HEADS + h)) * D_K + dh) * SEQ + s) = val;
        }
    }
}

// fused Q/K/V projections: grid.z selects tensor (768 blocks)
__global__ __launch_bounds__(256) void qkv_kernel(
    const ushort_t* __restrict__ Qb, const ushort_t* __restrict__ Kb,
    const ushort_t* __restrict__ Vb,
    const ushort_t* __restrict__ Wq, const ushort_t* __restrict__ Wk,
    const ushort_t* __restrict__ Wv,
    const ushort_t* __restrict__ bq, const ushort_t* __restrict__ bk,
    const ushort_t* __restrict__ bv,
    ushort_t* __restrict__ qn, ushort_t* __restrict__ kn,
    ushort_t* __restrict__ vT)
{
    __shared__ __align__(16) ushort_t smem[2 * (128 + 128) * 64];  // 64 KB
    const int z = blockIdx.z;
    if (z == 0)
        gemm_body<128, 1>(smem, Qb, Wq, bq, qn, nullptr, blockIdx.x, blockIdx.y);
    else if (z == 1)
        gemm_body<128, 1>(smem, Kb, Wk, bk, kn, nullptr, blockIdx.x, blockIdx.y);
    else
        gemm_body<128, 2>(smem, Vb, Wv, bv, vT, nullptr, blockIdx.x, blockIdx.y);
}

// output projection: BM=64 -> 512 blocks
__global__ __launch_bounds__(256) void wo_kernel(
    const ushort_t* __restrict__ A, const ushort_t* __restrict__ W,
    const ushort_t* __restrict__ bias, float* __restrict__ outf)
{
    __shared__ __align__(16) ushort_t smem[2 * (64 + 128) * 64];   // 48 KB
    gemm_body<64, 0>(smem, A, W, bias, nullptr, outf, blockIdx.x, blockIdx.y);
}

// ---------------------------------------------------------------------------
// Attention: per (b,h): out = (qn kn^T)^2 v. 64-q-row blocks (1024 blocks),
// 4 waves x 16 q-rows. 2-deep DMA pipeline on 64-wide k-tiles (4 DMAs/wave
// per tile -> vmcnt(4)). Per-wave P relayout with wave-local lgkm fence.
// ---------------------------------------------------------------------------
__global__ __launch_bounds__(256) void attn_kernel(
    const ushort_t* __restrict__ qn,
    const ushort_t* __restrict__ kn,
    const ushort_t* __restrict__ vT,
    ushort_t* __restrict__ attn_out)
{
    // buf i: kst = smem + i*8192 [64 j][64 d], vst = +4096 [64 d][64 j]
    __shared__ __align__(16) ushort_t smem[2 * 8192 + 4 * 16 * 72];  // 41 KB

    const int t    = threadIdx.x;
    const int wave = t >> 6;
    const int lane = t & 63;
    const int quad = lane >> 4;
    const int lc   = lane & 15;
    const int qt   = blockIdx.x;       // 0..31
    const int bh   = blockIdx.y;       // 0..31
    const int b    = bh >> 4;
    const int h    = bh & 15;

    const ushort_t* qb = qn + (size_t)bh * SEQ * D_K;
    const ushort_t* kb = kn + (size_t)bh * SEQ * D_K;
    const ushort_t* vb = vT + (size_t)bh * D_K * SEQ;
    const int q0 = qt * 64 + wave * 16;

    // q A-frags, reused across all 32 k-tiles (loaded before DMA issue)
    s16x8 aq[2];
#pragma unroll
    for (int ks = 0; ks < 2; ++ks)
        aq[ks] = *(const s16x8*)(qb + (size_t)(q0 + lc) * D_K + ks * 32 + quad * 8);

    f32x4 oacc[4];
    const f32x4 zero = {0.f, 0.f, 0.f, 0.f};
#pragma unroll
    for (int df = 0; df < 4; ++df) oacc[df] = zero;

    ushort_t* pl = smem + 2 * 8192 + wave * 16 * 72;  // per-wave [16 q][72]

    auto stage = [&](int buf, int j0) {
        ushort_t* kst = smem + buf * 8192;
        ushort_t* vst = kst + 4096;
#pragma unroll
        for (int c = 0; c < 2; ++c) {
            int idx = c * 256 + t;
            int row = idx >> 3, phys = idx & 7;
            int col = (phys ^ (row & 7)) * 8;
            gload_lds16(kb + (size_t)(j0 + row) * D_K + col, kst + idx * 8);
            gload_lds16(vb + (size_t)row * SEQ + j0 + col, vst + idx * 8);
        }
    };
    auto comp = [&](int buf) {
        ushort_t* kst = smem + buf * 8192;
        ushort_t* vst = kst + 4096;
        const int ph0 = ((0 * 4 + quad) ^ (lc & 7)) * 8;
        const int ph1 = ((1 * 4 + quad) ^ (lc & 7)) * 8;
        s16x8 bk[4][2];
#pragma unroll
        for (int jf = 0; jf < 4; ++jf) {
            bk[jf][0] = *(const s16x8*)(kst + (jf * 16 + lc) * 64 + ph0);
            bk[jf][1] = *(const s16x8*)(kst + (jf * 16 + lc) * 64 + ph1);
        }
        f32x4 s[4];
#pragma unroll
        for (int jf = 0; jf < 4; ++jf) {
            s[jf] = zero;
#pragma unroll
            for (int ks = 0; ks < 2; ++ks)
                s[jf] = __builtin_amdgcn_mfma_f32_16x16x32_bf16(aq[ks], bk[jf][ks], s[jf], 0, 0, 0);
        }
#pragma unroll
        for (int jf = 0; jf < 4; ++jf)
#pragma unroll
            for (int r = 0; r < 4; ++r)
                pl[(quad * 4 + r) * 72 + jf * 16 + lc] = f2bf(s[jf][r] * s[jf][r]);
        s16x8 bvf[4][2];
#pragma unroll
        for (int df = 0; df < 4; ++df) {
            bvf[df][0] = *(const s16x8*)(vst + (df * 16 + lc) * 64 + ph0);
            bvf[df][1] = *(const s16x8*)(vst + (df * 16 + lc) * 64 + ph1);
        }
        WAIT_LGKM0;   // pl writes visible wave-locally
        s16x8 aa[2];
#pragma unroll
        for (int ks = 0; ks < 2; ++ks)
            aa[ks] = *(const s16x8*)(pl + lc * 72 + ks * 32 + quad * 8);
#pragma unroll
        for (int df = 0; df < 4; ++df)
#pragma unroll
            for (int ks = 0; ks < 2; ++ks)
                oacc[df] = __builtin_amdgcn_mfma_f32_16x16x32_bf16(
                    aa[ks], bvf[df][ks], oacc[df], 0, 0, 0);
    };

    constexpr int NT = 32;
    stage(0, 0);
    stage(1, 64);
    for (int it = 0; it < NT - 2; ++it) {
        WAIT_VM(4);
        BARRIER;
        comp(it & 1);
        WAIT_LGKM0;
        BARRIER;
        stage(it & 1, (it + 2) * 64);
    }
    WAIT_VM(4);
    BARRIER;
    comp((NT - 2) & 1);
    WAIT_VM(0);
    BARRIER;
    comp((NT - 1) & 1);

    // store to (B,S,D) head-interleaved bf16 for the output projection
#pragma unroll
    for (int df = 0; df < 4; ++df)
#pragma unroll
        for (int r = 0; r < 4; ++r) {
            int s = q0 + quad * 4 + r;
            int d = df * 16 + lc;
            attn_out[((size_t)(b * SEQ + s)) * D_MODEL + h * D_K + d] =
                f2bf(oacc[df][r]);
        }
}

extern "C" void kernel_launch(void* const* d_in, const int* in_sizes, int n_in,
                              void* d_out, int out_size, void* d_ws, size_t ws_size,
                              hipStream_t stream)
{
    const float* Qf   = (const float*)d_in[0];
    const float* Kf   = (const float*)d_in[1];
    const float* Vf   = (const float*)d_in[2];
    const float* Wqf  = (const float*)d_in[3];
    const float* Wqbf = (const float*)d_in[4];
    const float* Wkf  = (const float*)d_in[5];
    const float* Wkbf = (const float*)d_in[6];
    const float* Wvf  = (const float*)d_in[7];
    const float* Wvbf = (const float*)d_in[8];
    const float* Wof  = (const float*)d_in[9];
    const float* Wobf = (const float*)d_in[10];

    const size_t NM = (size_t)M_TOT * D_MODEL;
    const size_t NW = (size_t)D_MODEL * D_MODEL;
    const size_t NB = D_MODEL;

    ushort_t* p = (ushort_t*)d_ws;
    ushort_t* Qb  = p;  p += NM;
    ushort_t* Kb  = p;  p += NM;
    ushort_t* Vb  = p;  p += NM;
    ushort_t* Wq  = p;  p += NW;
    ushort_t* Wk  = p;  p += NW;
    ushort_t* Wv  = p;  p += NW;
    ushort_t* Wo  = p;  p += NW;
    ushort_t* bq  = p;  p += NB;
    ushort_t* bk  = p;  p += NB;
    ushort_t* bvv = p;  p += NB;
    ushort_t* bo  = p;  p += NB;
    ushort_t* qn  = p;  p += NM;   // (B,H,S,DK)
    ushort_t* kn  = p;  p += NM;   // (B,H,S,DK)
    ushort_t* vT  = p;  p += NM;   // (B,H,DK,S)
    ushort_t* ao  = p;  p += NM;   // (B,S,D)

    ConvArgs ca;
    ca.src[0] = Qf;   ca.dst[0] = Qb;  ca.n[0] = (int)NM;
    ca.src[1] = Kf;   ca.dst[1] = Kb;  ca.n[1] = (int)NM;
    ca.src[2] = Vf;   ca.dst[2] = Vb;  ca.n[2] = (int)NM;
    ca.src[3] = Wqf;  ca.dst[3] = Wq;  ca.n[3] = (int)NW;
    ca.src[4] = Wkf;  ca.dst[4] = Wk;  ca.n[4] = (int)NW;
    ca.src[5] = Wvf;  ca.dst[5] = Wv;  ca.n[5] = (int)NW;
    ca.src[6] = Wof;  ca.dst[6] = Wo;  ca.n[6] = (int)NW;
    ca.src[7] = Wqbf; ca.dst[7] = bq;  ca.n[7] = (int)NB;
    ca.src[8] = Wkbf; ca.dst[8] = bk;  ca.n[8] = (int)NB;
    ca.src[9] = Wvbf; ca.dst[9] = bvv; ca.n[9] = (int)NB;
    ca.src[10] = Wobf; ca.dst[10] = bo; ca.n[10] = (int)NB;

    dim3 blk(256);
    convert_kernel<<<dim3((unsigned)(NM / (256 * 4)), 11), blk, 0, stream>>>(ca);

    qkv_kernel<<<dim3(M_TOT / 128, D_MODEL / 128, 3), blk, 0, stream>>>(
        Qb, Kb, Vb, Wq, Wk, Wv, bq, bk, bvv, qn, kn, vT);
    attn_kernel<<<dim3(SEQ / 64, BATCH * N_HEADS), blk, 0, stream>>>(qn, kn, vT, ao);
    wo_kernel<<<dim3(M_TOT / 64, D_MODEL / 128), blk, 0, stream>>>(
        ao, Wo, bo, (float*)d_out);
}